// Round 1
// baseline (422.909 us; speedup 1.0000x reference)
//
#include <hip/hip_runtime.h>
#include <cstddef>

#define IN_DIM 256
#define H_DIM  128
#define C_DIM  40
#define BM     64
#define BK     32
#define LDA    68    // BM+4: multiple of 4 floats -> float4-aligned rows
#define LDH    132   // H_DIM+4

// ---------------------------------------------------------------------------
// Build CSR row_ptr from sorted edge_dst via per-node lower_bound.
// ---------------------------------------------------------------------------
__global__ void build_row_ptr_kernel(const int* __restrict__ dst, int E,
                                     int* __restrict__ row_ptr, int n1) {
  int n = blockIdx.x * blockDim.x + threadIdx.x;
  if (n >= n1) return;
  int lo = 0, hi = E;
  while (lo < hi) {
    int mid = (lo + hi) >> 1;
    if (dst[mid] < n) lo = mid + 1; else hi = mid;
  }
  row_ptr[n] = lo;
}

// ---------------------------------------------------------------------------
// Fused dense: out[n][0:40] = relu(feat[n] @ W1) @ W2
// Block: 256 threads, 64-node tile. Phase 1: 64x128 GEMM (BK=32, 4x8 register
// tile/thread). Phase 2: h1 -> LDS, W2 -> LDS, 2x5 register tile/thread.
// ---------------------------------------------------------------------------
__global__ __launch_bounds__(256, 2) void fused_dense_kernel(
    const float* __restrict__ feat, const float* __restrict__ W1,
    const float* __restrict__ W2, float* __restrict__ out, int N) {
  __shared__ float smem[BM * LDH + H_DIM * C_DIM];  // 13568 floats = 54.3 KB
  float* ldsA  = smem;              // phase1: [BK][LDA]  feat^T tile
  float* ldsB  = smem + BK * LDA;   // phase1: [BK][H_DIM] W1 tile
  float* ldsH  = smem;              // phase2: [BM][LDH]  relu(h1)
  float* ldsW2 = smem + BM * LDH;   // phase2: [H_DIM][C_DIM]

  const int t  = threadIdx.x;
  const int tx = t & 15;            // col group: cols tx*8 .. +7
  const int ty = t >> 4;            // node group: nodes ty*4 .. +3
  const int nb = blockIdx.x * BM;

  float acc[4][8];
#pragma unroll
  for (int i = 0; i < 4; ++i)
#pragma unroll
    for (int j = 0; j < 8; ++j) acc[i][j] = 0.f;

  // staging assignments
  const int lrow = t >> 2;          // 0..63 (node within tile)
  const int lkq  = (t & 3) << 3;    // k offset 0,8,16,24
  int grow = nb + lrow;
  if (grow > N - 1) grow = N - 1;   // clamp: results for OOB rows discarded
  const float* frow = feat + (size_t)grow * IN_DIM;
  const int wkr = t >> 3;           // 0..31
  const int wcq = (t & 7) << 4;     // 0,16,...,112

  for (int kc = 0; kc < IN_DIM; kc += BK) {
    // stage feat (transposed) and W1 tile
    float4 f0 = *(const float4*)(frow + kc + lkq);
    float4 f1 = *(const float4*)(frow + kc + lkq + 4);
    const float* w1p = W1 + (size_t)(kc + wkr) * H_DIM + wcq;
    float4 b0 = *(const float4*)(w1p + 0);
    float4 b1 = *(const float4*)(w1p + 4);
    float4 b2 = *(const float4*)(w1p + 8);
    float4 b3 = *(const float4*)(w1p + 12);

    ldsA[(lkq + 0) * LDA + lrow] = f0.x;
    ldsA[(lkq + 1) * LDA + lrow] = f0.y;
    ldsA[(lkq + 2) * LDA + lrow] = f0.z;
    ldsA[(lkq + 3) * LDA + lrow] = f0.w;
    ldsA[(lkq + 4) * LDA + lrow] = f1.x;
    ldsA[(lkq + 5) * LDA + lrow] = f1.y;
    ldsA[(lkq + 6) * LDA + lrow] = f1.z;
    ldsA[(lkq + 7) * LDA + lrow] = f1.w;
    *(float4*)(ldsB + wkr * H_DIM + wcq +  0) = b0;
    *(float4*)(ldsB + wkr * H_DIM + wcq +  4) = b1;
    *(float4*)(ldsB + wkr * H_DIM + wcq +  8) = b2;
    *(float4*)(ldsB + wkr * H_DIM + wcq + 12) = b3;
    __syncthreads();

#pragma unroll 8
    for (int kk = 0; kk < BK; ++kk) {
      float4 av  = *(const float4*)(ldsA + kk * LDA + (ty << 2));
      float4 bv0 = *(const float4*)(ldsB + kk * H_DIM + (tx << 3));
      float4 bv1 = *(const float4*)(ldsB + kk * H_DIM + (tx << 3) + 4);
      float a[4] = {av.x, av.y, av.z, av.w};
      float b[8] = {bv0.x, bv0.y, bv0.z, bv0.w, bv1.x, bv1.y, bv1.z, bv1.w};
#pragma unroll
      for (int i = 0; i < 4; ++i)
#pragma unroll
        for (int j = 0; j < 8; ++j) acc[i][j] = fmaf(a[i], b[j], acc[i][j]);
    }
    __syncthreads();
  }

  // ---- phase 2: relu(h1) -> LDS ----
#pragma unroll
  for (int i = 0; i < 4; ++i) {
    int n = (ty << 2) + i;
#pragma unroll
    for (int j = 0; j < 8; ++j) {
      float v = acc[i][j];
      ldsH[n * LDH + (tx << 3) + j] = v > 0.f ? v : 0.f;
    }
  }
  // stage W2 (5120 floats, 20 per thread, coalesced float4)
#pragma unroll
  for (int i = 0; i < 5; ++i) {
    int off = i * 1024 + t * 4;
    *(float4*)(ldsW2 + off) = *(const float4*)(W2 + off);
  }
  __syncthreads();

  // GEMM2: thread -> 2 nodes x 5 cols
  const int cx = t & 7;    // cols cx*5 .. +4
  const int ny = t >> 3;   // nodes ny*2, ny*2+1
  float racc[2][5];
#pragma unroll
  for (int i = 0; i < 2; ++i)
#pragma unroll
    for (int j = 0; j < 5; ++j) racc[i][j] = 0.f;

#pragma unroll 4
  for (int k = 0; k < H_DIM; ++k) {
    float h0 = ldsH[((ny << 1) + 0) * LDH + k];
    float h1 = ldsH[((ny << 1) + 1) * LDH + k];
#pragma unroll
    for (int j = 0; j < 5; ++j) {
      float w = ldsW2[k * C_DIM + cx * 5 + j];
      racc[0][j] = fmaf(h0, w, racc[0][j]);
      racc[1][j] = fmaf(h1, w, racc[1][j]);
    }
  }
#pragma unroll
  for (int i = 0; i < 2; ++i) {
    int n = nb + (ny << 1) + i;
    if (n < N) {
#pragma unroll
      for (int j = 0; j < 5; ++j)
        out[(size_t)n * C_DIM + cx * 5 + j] = racc[i][j];
    }
  }
}

// ---------------------------------------------------------------------------
// SPMM (CSR, dst-sorted): one wave per destination node, lanes 0..39 = cols.
// No atomics. 4-edge unroll for memory-level parallelism.
// ---------------------------------------------------------------------------
__global__ __launch_bounds__(256) void spmm_kernel(
    const int* __restrict__ row_ptr, const int* __restrict__ esrc,
    const float* __restrict__ eval, const float* __restrict__ x,
    float* __restrict__ z, int N) {
  int node = (blockIdx.x << 2) + (threadIdx.x >> 6);
  if (node >= N) return;
  int lane = threadIdx.x & 63;
  int c = lane < C_DIM ? lane : 0;   // clamp keeps address in-bounds
  int e   = row_ptr[node];
  int end = row_ptr[node + 1];
  float acc = 0.f;
  for (; e + 4 <= end; e += 4) {
    int   s0 = esrc[e + 0], s1 = esrc[e + 1], s2 = esrc[e + 2], s3 = esrc[e + 3];
    float v0 = eval[e + 0], v1 = eval[e + 1], v2 = eval[e + 2], v3 = eval[e + 3];
    float x0 = x[s0 * C_DIM + c];
    float x1 = x[s1 * C_DIM + c];
    float x2 = x[s2 * C_DIM + c];
    float x3 = x[s3 * C_DIM + c];
    acc = fmaf(v0, x0, acc);
    acc = fmaf(v1, x1, acc);
    acc = fmaf(v2, x2, acc);
    acc = fmaf(v3, x3, acc);
  }
  for (; e < end; ++e) acc = fmaf(eval[e], x[esrc[e] * C_DIM + c], acc);
  if (lane < C_DIM) z[(size_t)node * C_DIM + lane] = acc;
}

// ---------------------------------------------------------------------------
extern "C" void kernel_launch(void* const* d_in, const int* in_sizes, int n_in,
                              void* d_out, int out_size, void* d_ws, size_t ws_size,
                              hipStream_t stream) {
  const float* feat = (const float*)d_in[0];
  const float* W1   = (const float*)d_in[1];
  const float* W2   = (const float*)d_in[2];
  const int*   esrc = (const int*)d_in[3];
  const int*   edst = (const int*)d_in[4];
  const float* evalp = (const float*)d_in[5];
  float* out = (float*)d_out;

  const int N = in_sizes[0] / IN_DIM;   // 100000
  const int E = in_sizes[3];            // 1600000

  // workspace layout: z1 [N*40] f32, then row_ptr [N+1] int
  float* z1 = (float*)d_ws;
  int* row_ptr = (int*)((char*)d_ws + (size_t)N * C_DIM * sizeof(float));

  // 1. CSR row_ptr from sorted edge_dst
  build_row_ptr_kernel<<<(N + 1 + 255) / 256, 256, 0, stream>>>(edst, E, row_ptr, N + 1);

  // 2. fused dense MLP -> h2 directly into d_out
  fused_dense_kernel<<<(N + BM - 1) / BM, 256, 0, stream>>>(feat, W1, W2, out, N);

  // 3. propagation round 1: d_out -> z1 (ws)
  spmm_kernel<<<(N + 3) / 4, 256, 0, stream>>>(row_ptr, esrc, evalp, out, z1, N);

  // 4. propagation round 2: z1 -> d_out
  spmm_kernel<<<(N + 3) / 4, 256, 0, stream>>>(row_ptr, esrc, evalp, z1, out, N);
}

// Round 2
// 337.907 us; speedup vs baseline: 1.2516x; 1.2516x over previous
//
#include <hip/hip_runtime.h>
#include <cstddef>
#include <cstdint>

#define IN_DIM 256
#define H_DIM  128
#define C_DIM  40
#define BM     128
#define BK     64
#define LDT    72    // ushort stride for A/B LDS tiles: 144 B (16B-aligned, <=4-way bank alias)
#define LDH2   132   // ushort stride for h LDS tile
#define PAD_C  64    // padded column count for bf16 intermediates (1 cache line/row)

typedef short bf16x8 __attribute__((ext_vector_type(8)));
typedef float f32x16 __attribute__((ext_vector_type(16)));

__device__ __forceinline__ ushort f2bf(float f) {   // RNE fp32 -> bf16
  uint u = __builtin_bit_cast(uint, f);
  u += 0x7fffu + ((u >> 16) & 1u);
  return (ushort)(u >> 16);
}
__device__ __forceinline__ float bf2f(ushort s) {
  uint u = ((uint)s) << 16;
  return __builtin_bit_cast(float, u);
}

// ---------------------------------------------------------------------------
// CSR row_ptr from sorted edge_dst (lower_bound per node).
// ---------------------------------------------------------------------------
__global__ void build_row_ptr_kernel(const int* __restrict__ dst, int E,
                                     int* __restrict__ row_ptr, int n1) {
  int n = blockIdx.x * blockDim.x + threadIdx.x;
  if (n >= n1) return;
  int lo = 0, hi = E;
  while (lo < hi) {
    int mid = (lo + hi) >> 1;
    if (dst[mid] < n) lo = mid + 1; else hi = mid;
  }
  row_ptr[n] = lo;
}

// ---------------------------------------------------------------------------
// W1 [256][128] fp32 -> W1t [128][256] bf16 (B^T layout for MFMA staging).
// ---------------------------------------------------------------------------
__global__ void convert_w1_kernel(const float* __restrict__ W1,
                                  ushort* __restrict__ w1t) {
  int tid = blockIdx.x * blockDim.x + threadIdx.x;  // 0..32767
  int k = tid >> 7, n = tid & 127;
  w1t[n * IN_DIM + k] = f2bf(W1[tid]);
}

// ---------------------------------------------------------------------------
// Fused dense MLP: z0[n][0:40] = relu(feat[n] @ W1) @ W2, bf16-padded output.
// Block 256 thr (4 waves), 128-node tile.
// Phase 1: h1 = feat @ W1 via mfma_f32_32x32x16_bf16; wave w owns node rows
//          32w..32w+31, all 128 hidden cols (4 col-tiles), acc = 4 x f32x16.
// Phase 2: relu(h1) -> LDS bf16, W2 -> LDS fp32, VALU GEMM2, write z0.
// ---------------------------------------------------------------------------
__global__ __launch_bounds__(256, 2) void fused_dense_kernel(
    const float* __restrict__ feat, const ushort* __restrict__ w1t,
    const float* __restrict__ W2, ushort* __restrict__ z0, int N) {
  // phase1: A tile [128][LDT], B tile [128][LDT]  (36864 B)
  // phase2: ldsH [128][LDH2] bf16 (33792 B) + ldsW2 [128*40] fp32 (20480 B)
  __shared__ __align__(16) ushort smem[27136];  // 54272 B -> 2 blocks/CU

  const int t = threadIdx.x;
  const int w = t >> 6, l = t & 63;
  const int nb = blockIdx.x * BM;

  f32x16 acc[4];
#pragma unroll
  for (int tn = 0; tn < 4; ++tn)
#pragma unroll
    for (int r = 0; r < 16; ++r) acc[tn][r] = 0.f;

  // staging assignment: thread -> (row, k-half)
  const int srow = t >> 1;           // 0..127
  const int skh  = (t & 1) << 5;     // 0 or 32
  int grow = nb + srow; if (grow >= N) grow = N - 1;
  const float*  fp = feat + (size_t)grow * IN_DIM + skh;
  const ushort* wp = w1t + (srow << 8) + skh;

  // frag base addresses (constant across K loop)
  const ushort* Abase = smem + (w * 32 + (l & 31)) * LDT + ((l >> 5) << 3);
  const ushort* Bbase = smem + 128 * LDT + (l & 31) * LDT + ((l >> 5) << 3);

  for (int kc = 0; kc < IN_DIM; kc += BK) {
    // stage A: 8xfloat4 fp32 -> 32 bf16 -> 4x uint4 LDS store
    const float4* f4 = (const float4*)(fp + kc);
    uint* adst = (uint*)(smem + srow * LDT + skh);
#pragma unroll
    for (int i = 0; i < 4; ++i) {
      float4 v0 = f4[2 * i], v1 = f4[2 * i + 1];
      uint4 pk;
      pk.x = (uint)f2bf(v0.x) | ((uint)f2bf(v0.y) << 16);
      pk.y = (uint)f2bf(v0.z) | ((uint)f2bf(v0.w) << 16);
      pk.z = (uint)f2bf(v1.x) | ((uint)f2bf(v1.y) << 16);
      pk.w = (uint)f2bf(v1.z) | ((uint)f2bf(v1.w) << 16);
      ((uint4*)adst)[i] = pk;
    }
    // stage B: 4x uint4 copy from pre-converted bf16 W1t
    const uint4* bsrc = (const uint4*)(wp + kc);
    uint4* bdst = (uint4*)(smem + 128 * LDT + srow * LDT + skh);
#pragma unroll
    for (int i = 0; i < 4; ++i) bdst[i] = bsrc[i];
    __syncthreads();

#pragma unroll
    for (int ks = 0; ks < 4; ++ks) {
      bf16x8 af = *(const bf16x8*)(Abase + ks * 16);
#pragma unroll
      for (int tn = 0; tn < 4; ++tn) {
        bf16x8 bfr = *(const bf16x8*)(Bbase + tn * 32 * LDT + ks * 16);
        acc[tn] = __builtin_amdgcn_mfma_f32_32x32x16_bf16(af, bfr, acc[tn], 0, 0, 0);
      }
    }
    __syncthreads();
  }

  // ---- phase 2: relu(h1) -> ldsH (bf16), C/D layout: col=l&31, row=(r&3)+8*(r>>2)+4*(l>>5)
#pragma unroll
  for (int tn = 0; tn < 4; ++tn) {
    int col = tn * 32 + (l & 31);
#pragma unroll
    for (int r = 0; r < 16; ++r) {
      int node = (r & 3) + 8 * (r >> 2) + 4 * (l >> 5) + 32 * w;
      float v = acc[tn][r];
      smem[node * LDH2 + col] = f2bf(v > 0.f ? v : 0.f);
    }
  }
  float* ldsW2 = (float*)(smem + 128 * LDH2);
#pragma unroll
  for (int i = 0; i < 5; ++i) {
    int off = i * 1024 + t * 4;
    *(float4*)(ldsW2 + off) = *(const float4*)(W2 + off);
  }
  __syncthreads();

  // GEMM2: thread -> 4 nodes x 5 cols, k unrolled by 2 (packed bf16 reads)
  const int ng = t >> 3;            // node group: nodes ng*4..+3
  const int cg = (t & 7) * 5;       // col base
  float acc2[4][5];
#pragma unroll
  for (int i = 0; i < 4; ++i)
#pragma unroll
    for (int j = 0; j < 5; ++j) acc2[i][j] = 0.f;

  for (int k = 0; k < H_DIM; k += 2) {
    float w2a[5], w2b[5];
#pragma unroll
    for (int j = 0; j < 5; ++j) {
      w2a[j] = ldsW2[k * C_DIM + cg + j];
      w2b[j] = ldsW2[(k + 1) * C_DIM + cg + j];
    }
#pragma unroll
    for (int i = 0; i < 4; ++i) {
      uint hv = *(const uint*)(smem + (ng * 4 + i) * LDH2 + k);
      float h0 = bf2f((ushort)(hv & 0xffffu));
      float h1 = bf2f((ushort)(hv >> 16));
#pragma unroll
      for (int j = 0; j < 5; ++j) {
        acc2[i][j] = fmaf(h0, w2a[j], acc2[i][j]);
        acc2[i][j] = fmaf(h1, w2b[j], acc2[i][j]);
      }
    }
  }

#pragma unroll
  for (int i = 0; i < 4; ++i) {
    int node = nb + ng * 4 + i;
    if (node < N) {
      ushort* zp = z0 + (size_t)node * PAD_C + cg;
#pragma unroll
      for (int j = 0; j < 5; ++j) zp[j] = f2bf(acc2[i][j]);
    }
  }
  // zero the pad cols 40..63 (so spmm gather lanes 40-63 accumulate 0)
  {
    int node = nb + (t >> 1);
    if (node < N) {
      uint* zp = (uint*)(z0 + (size_t)node * PAD_C + 40) + (t & 1) * 6;
#pragma unroll
      for (int j = 0; j < 6; ++j) zp[j] = 0u;
    }
  }
}

// ---------------------------------------------------------------------------
// SPMM (CSR, dst-sorted): wave per node; 64 lanes = 64 padded bf16 cols
// (one aligned 128-B line per edge). 8-edge unroll for MLP. No atomics.
// out_f32=0: write bf16 padded z; out_f32=1: write fp32 [N][40].
// ---------------------------------------------------------------------------
__global__ __launch_bounds__(256) void spmm_kernel(
    const int* __restrict__ row_ptr, const int* __restrict__ esrc,
    const float* __restrict__ eval, const ushort* __restrict__ x,
    ushort* __restrict__ zb, float* __restrict__ zf, int N, int out_f32) {
  int node = (blockIdx.x << 2) + (threadIdx.x >> 6);
  if (node >= N) return;
  int lane = threadIdx.x & 63;
  int e = row_ptr[node], end = row_ptr[node + 1];
  float acc = 0.f;
  for (; e + 8 <= end; e += 8) {
    int s[8]; float v[8]; float xv[8];
#pragma unroll
    for (int i = 0; i < 8; ++i) s[i] = esrc[e + i];
#pragma unroll
    for (int i = 0; i < 8; ++i) v[i] = eval[e + i];
#pragma unroll
    for (int i = 0; i < 8; ++i) xv[i] = bf2f(x[s[i] * PAD_C + lane]);
#pragma unroll
    for (int i = 0; i < 8; ++i) acc = fmaf(v[i], xv[i], acc);
  }
  for (; e < end; ++e) acc = fmaf(eval[e], bf2f(x[esrc[e] * PAD_C + lane]), acc);
  if (out_f32) {
    if (lane < C_DIM) zf[(size_t)node * C_DIM + lane] = acc;
  } else {
    zb[(size_t)node * PAD_C + lane] = f2bf(acc);
  }
}

// ---------------------------------------------------------------------------
extern "C" void kernel_launch(void* const* d_in, const int* in_sizes, int n_in,
                              void* d_out, int out_size, void* d_ws, size_t ws_size,
                              hipStream_t stream) {
  const float* feat  = (const float*)d_in[0];
  const float* W1    = (const float*)d_in[1];
  const float* W2    = (const float*)d_in[2];
  const int*   esrc  = (const int*)d_in[3];
  const int*   edst  = (const int*)d_in[4];
  const float* evalp = (const float*)d_in[5];
  float* out = (float*)d_out;

  const int N = in_sizes[0] / IN_DIM;   // 100000
  const int E = in_sizes[3];            // 1600000

  // ws layout: z0 bf16 [N][64] | z1 bf16 [N][64] | W1t bf16 [128][256] | row_ptr [N+1]
  char* ws = (char*)d_ws;
  ushort* z0  = (ushort*)ws;
  ushort* z1  = (ushort*)(ws + (size_t)N * PAD_C * 2);
  ushort* w1t = (ushort*)(ws + (size_t)N * PAD_C * 4);
  int* row_ptr = (int*)(ws + (size_t)N * PAD_C * 4 + (size_t)IN_DIM * H_DIM * 2);

  build_row_ptr_kernel<<<(N + 256) / 256, 256, 0, stream>>>(edst, E, row_ptr, N + 1);
  convert_w1_kernel<<<(IN_DIM * H_DIM) / 256, 256, 0, stream>>>(W1, w1t);
  fused_dense_kernel<<<(N + BM - 1) / BM, 256, 0, stream>>>(feat, w1t, W2, z0, N);
  spmm_kernel<<<(N + 3) / 4, 256, 0, stream>>>(row_ptr, esrc, evalp, z0, z1, nullptr, N, 0);
  spmm_kernel<<<(N + 3) / 4, 256, 0, stream>>>(row_ptr, esrc, evalp, z1, nullptr, out, N, 1);
}

// Round 4
// 286.070 us; speedup vs baseline: 1.4783x; 1.1812x over previous
//
#include <hip/hip_runtime.h>
#include <cstddef>
#include <cstdint>

#define IN_DIM 256
#define H_DIM  128
#define C_DIM  40
#define BM     128
#define BK     64
#define LDT    72    // ushort stride, phase-1 A/B tiles (144 B rows, measured 0 conflicts)
#define LDH    136   // ushort stride, phase-2 h / w2 tiles (272 B rows, same bank class)
#define PAD_C  64    // padded column count for bf16 intermediates (1 cache line/row)

typedef short bf16x8 __attribute__((ext_vector_type(8)));
typedef float f32x16 __attribute__((ext_vector_type(16)));

__device__ __forceinline__ ushort f2bf(float f) {   // RNE fp32 -> bf16
  uint u = __builtin_bit_cast(uint, f);
  u += 0x7fffu + ((u >> 16) & 1u);
  return (ushort)(u >> 16);
}
__device__ __forceinline__ float bf2f(uint s) {     // low 16 bits -> f32
  uint u = s << 16;
  return __builtin_bit_cast(float, u);
}

// ---------------------------------------------------------------------------
// CSR row_ptr from sorted edge_dst (lower_bound per node).
// ---------------------------------------------------------------------------
__global__ void build_row_ptr_kernel(const int* __restrict__ dst, int E,
                                     int* __restrict__ row_ptr, int n1) {
  int n = blockIdx.x * blockDim.x + threadIdx.x;
  if (n >= n1) return;
  int lo = 0, hi = E;
  while (lo < hi) {
    int mid = (lo + hi) >> 1;
    if (dst[mid] < n) lo = mid + 1; else hi = mid;
  }
  row_ptr[n] = lo;
}

// ---------------------------------------------------------------------------
// W1 [256][128] f32 -> w1t [128][256] bf16 ; W2 [128][40] f32 -> w2t [64][128]
// bf16 (n-major, zero-padded n=40..63 so GEMM2 pad cols come out zero).
// ---------------------------------------------------------------------------
__global__ void convert_weights_kernel(const float* __restrict__ W1,
                                       const float* __restrict__ W2,
                                       ushort* __restrict__ w1t,
                                       ushort* __restrict__ w2t) {
  int tid = blockIdx.x * blockDim.x + threadIdx.x;  // 0..40959
  if (tid < IN_DIM * H_DIM) {
    int k = tid >> 7, n = tid & 127;
    w1t[n * IN_DIM + k] = f2bf(W1[tid]);
  } else {
    int i = tid - IN_DIM * H_DIM;                   // 0..8191
    int n = i >> 7, k = i & 127;
    w2t[i] = (n < C_DIM) ? f2bf(W2[k * C_DIM + n]) : (ushort)0;
  }
}

// ---------------------------------------------------------------------------
// Fused dense MLP: z0[n][0:64] = pad(relu(feat[n] @ W1) @ W2) bf16.
// Block 256 thr (4 waves), 128-node tile, 52224 B LDS -> 3 blocks/CU.
// Phase 1: h = feat @ W1 via mfma_32x32x16_bf16 (wave w: nodes 32w..+31,
//          4 col-tiles). Phase 2: relu(h) -> LDS A-layout rows, w2t -> LDS,
//          GEMM2 via 16 MFMA/wave, store C-frags to z0.
// ---------------------------------------------------------------------------
__global__ __launch_bounds__(256, 3) void fused_dense_kernel(
    const float* __restrict__ feat, const ushort* __restrict__ w1t,
    const ushort* __restrict__ w2t, ushort* __restrict__ z0, int N) {
  // phase1: A [128][LDT] + B [128][LDT]            = 36864 B
  // phase2: h [128][LDH] (34816 B) + w2 [64][LDH]  = 52224 B
  __shared__ __align__(16) ushort smem[26112];

  const int t = threadIdx.x;
  const int w = t >> 6, l = t & 63;
  const int nb = blockIdx.x * BM;

  f32x16 acc[4];
#pragma unroll
  for (int tn = 0; tn < 4; ++tn)
#pragma unroll
    for (int r = 0; r < 16; ++r) acc[tn][r] = 0.f;

  // staging assignment: thread -> (row 0..127, k-half 0/32)
  const int srow = t >> 1;
  const int skh  = (t & 1) << 5;
  int grow = nb + srow; if (grow >= N) grow = N - 1;
  const float*  fp = feat + (size_t)grow * IN_DIM + skh;
  const ushort* wp = w1t + (srow << 8) + skh;

  const ushort* Abase = smem + (w * 32 + (l & 31)) * LDT + ((l >> 5) << 3);
  const ushort* Bbase = smem + 128 * LDT + (l & 31) * LDT + ((l >> 5) << 3);

  for (int kc = 0; kc < IN_DIM; kc += BK) {
    const float4* f4 = (const float4*)(fp + kc);
    uint* adst = (uint*)(smem + srow * LDT + skh);
#pragma unroll
    for (int i = 0; i < 4; ++i) {
      float4 v0 = f4[2 * i], v1 = f4[2 * i + 1];
      uint4 pk;
      pk.x = (uint)f2bf(v0.x) | ((uint)f2bf(v0.y) << 16);
      pk.y = (uint)f2bf(v0.z) | ((uint)f2bf(v0.w) << 16);
      pk.z = (uint)f2bf(v1.x) | ((uint)f2bf(v1.y) << 16);
      pk.w = (uint)f2bf(v1.z) | ((uint)f2bf(v1.w) << 16);
      ((uint4*)adst)[i] = pk;
    }
    const uint4* bsrc = (const uint4*)(wp + kc);
    uint4* bdst = (uint4*)(smem + 128 * LDT + srow * LDT + skh);
#pragma unroll
    for (int i = 0; i < 4; ++i) bdst[i] = bsrc[i];
    __syncthreads();

#pragma unroll
    for (int ks = 0; ks < 4; ++ks) {
      bf16x8 af = *(const bf16x8*)(Abase + ks * 16);
#pragma unroll
      for (int tn = 0; tn < 4; ++tn) {
        bf16x8 bfr = *(const bf16x8*)(Bbase + tn * 32 * LDT + ks * 16);
        acc[tn] = __builtin_amdgcn_mfma_f32_32x32x16_bf16(af, bfr, acc[tn], 0, 0, 0);
      }
    }
    __syncthreads();
  }

  // ---- phase 2: relu(h) -> LDS rows [node][k], C-layout: col=l&31, node=(r&3)+8*(r>>2)+4*(l>>5)
#pragma unroll
  for (int tn = 0; tn < 4; ++tn) {
    int col = tn * 32 + (l & 31);
#pragma unroll
    for (int r = 0; r < 16; ++r) {
      int nodeLoc = (r & 3) + 8 * (r >> 2) + 4 * (l >> 5) + 32 * w;
      float v = acc[tn][r];
      smem[nodeLoc * LDH + col] = f2bf(v > 0.f ? v : 0.f);
    }
  }
  // stage w2t [64][128] -> LDS [64][LDH]: thread t copies 32 ushorts (4 uint4)
  {
    int row = t >> 2, c4 = (t & 3) << 5;
    const uint4* src = (const uint4*)(w2t + row * H_DIM + c4);
    uint4* dst = (uint4*)(smem + 128 * LDH + row * LDH + c4);
    dst[0] = src[0];
    dst[1] = src[1];
    dst[2] = src[2];
    dst[3] = src[3];
  }
  __syncthreads();

  // GEMM2: wave w -> nodes 32w..+31, n-tiles {0..31, 32..63}, K=128
  f32x16 acc2[2];
#pragma unroll
  for (int tn = 0; tn < 2; ++tn)
#pragma unroll
    for (int r = 0; r < 16; ++r) acc2[tn][r] = 0.f;

  const ushort* Hbase  = smem + (w * 32 + (l & 31)) * LDH + ((l >> 5) << 3);
  const ushort* W2base = smem + 128 * LDH + (l & 31) * LDH + ((l >> 5) << 3);
#pragma unroll
  for (int kb = 0; kb < 8; ++kb) {
    bf16x8 af = *(const bf16x8*)(Hbase + kb * 16);
#pragma unroll
    for (int tn = 0; tn < 2; ++tn) {
      bf16x8 bfr = *(const bf16x8*)(W2base + tn * 32 * LDH + kb * 16);
      acc2[tn] = __builtin_amdgcn_mfma_f32_32x32x16_bf16(af, bfr, acc2[tn], 0, 0, 0);
    }
  }

  // store z0 (pad cols 40..63 are zero because w2t rows 40..63 are zero)
#pragma unroll
  for (int tn = 0; tn < 2; ++tn) {
    int col = tn * 32 + (l & 31);
#pragma unroll
    for (int r = 0; r < 16; ++r) {
      int node = nb + 32 * w + (r & 3) + 8 * (r >> 2) + 4 * (l >> 5);
      if (node < N) z0[(size_t)node * PAD_C + col] = f2bf(acc2[tn][r]);
    }
  }
}

// ---------------------------------------------------------------------------
// SPMM (CSR, dst-sorted): one wave per node. 8 edges per gather instruction:
// lane = 8*h + j (h = edge slot 0..7, j = col-oct 0..7); each lane loads
// dwordx4 = 8 bf16 cols of edge slot h's source row -> 64 lanes x 16 B = 8
// full 128-B rows per instruction. Butterfly-reduce over slots at the end.
// ---------------------------------------------------------------------------
__global__ __launch_bounds__(256) void spmm_kernel(
    const int* __restrict__ row_ptr, const int* __restrict__ esrc,
    const float* __restrict__ eval, const ushort* __restrict__ x,
    ushort* __restrict__ zb, float* __restrict__ zf, int N, int out_f32) {
  int node = (blockIdx.x << 2) + (threadIdx.x >> 6);
  if (node >= N) return;
  const int lane = threadIdx.x & 63;
  const int h = lane >> 3;          // edge slot
  const int j = lane & 7;           // col oct: cols 8j..8j+7

  int e   = row_ptr[node];
  int end = row_ptr[node + 1];

  float acc[8];
#pragma unroll
  for (int c = 0; c < 8; ++c) acc[c] = 0.f;

  for (; e + 8 <= end; e += 8) {
    int   s = esrc[e + h];
    float v = eval[e + h];
    uint4 u = *(const uint4*)(x + (size_t)s * PAD_C + j * 8);
    acc[0] = fmaf(v, bf2f(u.x & 0xffffu), acc[0]);
    acc[1] = fmaf(v, bf2f(u.x >> 16),     acc[1]);
    acc[2] = fmaf(v, bf2f(u.y & 0xffffu), acc[2]);
    acc[3] = fmaf(v, bf2f(u.y >> 16),     acc[3]);
    acc[4] = fmaf(v, bf2f(u.z & 0xffffu), acc[4]);
    acc[5] = fmaf(v, bf2f(u.z >> 16),     acc[5]);
    acc[6] = fmaf(v, bf2f(u.w & 0xffffu), acc[6]);
    acc[7] = fmaf(v, bf2f(u.w >> 16),     acc[7]);
  }
  if (e < end) {                    // tail: clamp slots past the end, weight 0
    int ei = e + h;
    int ec = ei < end - 1 ? ei : end - 1;
    int   s = esrc[ec];
    float v = (ei < end) ? eval[ec] : 0.f;
    uint4 u = *(const uint4*)(x + (size_t)s * PAD_C + j * 8);
    acc[0] = fmaf(v, bf2f(u.x & 0xffffu), acc[0]);
    acc[1] = fmaf(v, bf2f(u.x >> 16),     acc[1]);
    acc[2] = fmaf(v, bf2f(u.y & 0xffffu), acc[2]);
    acc[3] = fmaf(v, bf2f(u.y >> 16),     acc[3]);
    acc[4] = fmaf(v, bf2f(u.z & 0xffffu), acc[4]);
    acc[5] = fmaf(v, bf2f(u.z >> 16),     acc[5]);
    acc[6] = fmaf(v, bf2f(u.w & 0xffffu), acc[6]);
    acc[7] = fmaf(v, bf2f(u.w >> 16),     acc[7]);
  }

  // reduce across the 8 edge slots (lane bits 3..5)
#pragma unroll
  for (int c = 0; c < 8; ++c) acc[c] += __shfl_xor(acc[c], 8);
#pragma unroll
  for (int c = 0; c < 8; ++c) acc[c] += __shfl_xor(acc[c], 16);
#pragma unroll
  for (int c = 0; c < 8; ++c) acc[c] += __shfl_xor(acc[c], 32);

  if (out_f32) {
    if (lane < 5) {                 // lanes 0..4: j=0..4 -> cols 0..39
      float4 o0 = {acc[0], acc[1], acc[2], acc[3]};
      float4 o1 = {acc[4], acc[5], acc[6], acc[7]};
      float* p = zf + (size_t)node * C_DIM + j * 8;
      *(float4*)(p + 0) = o0;
      *(float4*)(p + 4) = o1;
    }
  } else {
    if (lane < 8) {                 // lanes 0..7: j=0..7 -> cols 0..63
      uint4 p;
      p.x = (uint)f2bf(acc[0]) | ((uint)f2bf(acc[1]) << 16);
      p.y = (uint)f2bf(acc[2]) | ((uint)f2bf(acc[3]) << 16);
      p.z = (uint)f2bf(acc[4]) | ((uint)f2bf(acc[5]) << 16);
      p.w = (uint)f2bf(acc[6]) | ((uint)f2bf(acc[7]) << 16);
      *(uint4*)(zb + (size_t)node * PAD_C + j * 8) = p;
    }
  }
}

// ---------------------------------------------------------------------------
extern "C" void kernel_launch(void* const* d_in, const int* in_sizes, int n_in,
                              void* d_out, int out_size, void* d_ws, size_t ws_size,
                              hipStream_t stream) {
  const float* feat  = (const float*)d_in[0];
  const float* W1    = (const float*)d_in[1];
  const float* W2    = (const float*)d_in[2];
  const int*   esrc  = (const int*)d_in[3];
  const int*   edst  = (const int*)d_in[4];
  const float* evalp = (const float*)d_in[5];
  float* out = (float*)d_out;

  const int N = in_sizes[0] / IN_DIM;   // 100000
  const int E = in_sizes[3];            // 1600000

  // ws: z0 bf16 [N][64] | z1 bf16 [N][64] | w1t [128][256] | w2t [64][128] | row_ptr
  char* ws = (char*)d_ws;
  ushort* z0  = (ushort*)ws;
  ushort* z1  = (ushort*)(ws + (size_t)N * PAD_C * 2);
  ushort* w1t = (ushort*)(ws + (size_t)N * PAD_C * 4);
  ushort* w2t = w1t + IN_DIM * H_DIM;
  int* row_ptr = (int*)((char*)(w2t + PAD_C * H_DIM));

  build_row_ptr_kernel<<<(N + 256) / 256, 256, 0, stream>>>(edst, E, row_ptr, N + 1);
  convert_weights_kernel<<<(IN_DIM * H_DIM + PAD_C * H_DIM) / 256, 256, 0, stream>>>(
      W1, W2, w1t, w2t);
  fused_dense_kernel<<<(N + BM - 1) / BM, 256, 0, stream>>>(feat, w1t, w2t, z0, N);
  spmm_kernel<<<(N + 3) / 4, 256, 0, stream>>>(row_ptr, esrc, evalp, z0, z1, nullptr, N, 0);
  spmm_kernel<<<(N + 3) / 4, 256, 0, stream>>>(row_ptr, esrc, evalp, z1, nullptr, out, N, 1);
}